// Round 3
// baseline (163.691 us; speedup 1.0000x reference)
//
#include <hip/hip_runtime.h>
#include <hip/hip_bf16.h>

#define NEG_SLOPE 0.01f

constexpr int N_G  = 32;    // graphs
constexpr int V_N  = 1024;  // nodes per graph
constexpr int F_IN = 128;
constexpr int H_D  = 64;
constexpr int NV   = N_G * V_N;  // 32768

// ---------------------------------------------------------------------------
// Kernel 1: h = features @ W^T  (NV x 128) @ (128 x 64) -> (NV x 64)
// also s_src = h @ a[:64], s_dst = h @ a[64:]
// Block: 64 rows, 256 threads. thread = (row = tid&63, hq = tid>>6),
// each thread computes h[row][hq*16 .. hq*16+16).
// ---------------------------------------------------------------------------
__global__ __launch_bounds__(256) void gat_h_kernel(
    const float* __restrict__ feat,   // (NV, 128)
    const float* __restrict__ W,      // (64, 128)
    const float* __restrict__ a,      // (128)
    float* __restrict__ h,            // (NV, 64)
    float* __restrict__ s_src,        // (NV)
    float* __restrict__ s_dst)        // (NV)
{
    __shared__ float Fs[64][65];     // features half-tile, +1 pad (conflict-free)
    __shared__ float WsT[64][64];    // WsT[k][hh] transposed W half-tile
    __shared__ float red[2][4][64];  // s_src/s_dst partial reduction

    const int tid = threadIdx.x;
    const int row = tid & 63;
    const int hq  = tid >> 6;
    const int r0  = blockIdx.x * 64;

    float acc[16];
#pragma unroll
    for (int c = 0; c < 16; ++c) acc[c] = 0.f;

    for (int kh = 0; kh < 2; ++kh) {
        __syncthreads();
        // stage features half-tile: 64 rows x 64 k = 1024 float4, 4/thread
#pragma unroll
        for (int t = 0; t < 4; ++t) {
            int f4 = tid + t * 256;
            int rr = f4 >> 4;
            int kk = (f4 & 15) << 2;
            float4 v = *reinterpret_cast<const float4*>(
                feat + (size_t)(r0 + rr) * F_IN + kh * 64 + kk);
            Fs[rr][kk + 0] = v.x; Fs[rr][kk + 1] = v.y;
            Fs[rr][kk + 2] = v.z; Fs[rr][kk + 3] = v.w;
        }
        // stage W half-tile transposed: W[hh][kh*64+kk] -> WsT[kk][hh]
#pragma unroll
        for (int t = 0; t < 4; ++t) {
            int f4 = tid + t * 256;
            int hh = f4 >> 4;
            int kk = (f4 & 15) << 2;
            float4 v = *reinterpret_cast<const float4*>(
                W + (size_t)hh * F_IN + kh * 64 + kk);
            WsT[kk + 0][hh] = v.x; WsT[kk + 1][hh] = v.y;
            WsT[kk + 2][hh] = v.z; WsT[kk + 3][hh] = v.w;
        }
        __syncthreads();
#pragma unroll 8
        for (int k = 0; k < 64; ++k) {
            float fv = Fs[row][k];  // lanes: (row+k)%32 banks, 2-way -> free
            const float4* wrow = reinterpret_cast<const float4*>(&WsT[k][hq * 16]);
            float wv[16];
            *reinterpret_cast<float4*>(&wv[0])  = wrow[0];  // broadcast reads
            *reinterpret_cast<float4*>(&wv[4])  = wrow[1];
            *reinterpret_cast<float4*>(&wv[8])  = wrow[2];
            *reinterpret_cast<float4*>(&wv[12]) = wrow[3];
#pragma unroll
            for (int c = 0; c < 16; ++c) acc[c] += fv * wv[c];
        }
    }

    // s_src / s_dst partials over this thread's 16 columns
    float ps = 0.f, pd = 0.f;
#pragma unroll
    for (int c = 0; c < 16; ++c) {
        ps += acc[c] * a[hq * 16 + c];
        pd += acc[c] * a[H_D + hq * 16 + c];
    }
    red[0][hq][row] = ps;
    red[1][hq][row] = pd;

    // write h
#pragma unroll
    for (int c4 = 0; c4 < 4; ++c4) {
        float4 v = make_float4(acc[c4 * 4 + 0], acc[c4 * 4 + 1],
                               acc[c4 * 4 + 2], acc[c4 * 4 + 3]);
        *reinterpret_cast<float4*>(h + (size_t)(r0 + row) * H_D + hq * 16 + c4 * 4) = v;
    }
    __syncthreads();
    if (tid < 64) {
        s_src[r0 + tid] = red[0][0][tid] + red[0][1][tid] + red[0][2][tid] + red[0][3][tid];
    } else if (tid < 128) {
        int r = tid - 64;
        s_dst[r0 + r] = red[1][0][r] + red[1][1][r] + red[1][2][r] + red[1][3][r];
    }
}

// ---------------------------------------------------------------------------
// Kernel 2: fused leakyrelu-logits + softmax + att@h.
// Monotonicity: max_j leaky(ss_i + sd_j) = leaky(ss_i + max_j sd_j), so the
// row max is known upfront (no online rescale). Block = (n, 64-row i-tile),
// 256 threads; thread = (row = tid&63, hq = tid>>6) owns out[i0+row][hq*16..+16).
// ---------------------------------------------------------------------------
__global__ __launch_bounds__(256) void gat_attn_kernel(
    const float* __restrict__ h,      // (NV, 64)
    const float* __restrict__ s_src,  // (NV)
    const float* __restrict__ s_dst,  // (NV)
    float* __restrict__ out)          // (NV, 64)
{
    __shared__ float sd[V_N];        // 4 KB
    __shared__ float hs[128][64];    // 32 KB j-tile of h
    __shared__ float wred[4];

    const int tid = threadIdx.x;
    const int row = tid & 63;
    const int hq  = tid >> 6;
    const int n   = blockIdx.x >> 4;
    const int i0  = (blockIdx.x & 15) * 64;
    const size_t nbase = (size_t)n * V_N;

    // stage s_dst[n, :] and find its max
    float lm;
    {
        float4 v = *reinterpret_cast<const float4*>(s_dst + nbase + tid * 4);
        *reinterpret_cast<float4*>(&sd[tid * 4]) = v;
        lm = fmaxf(fmaxf(v.x, v.y), fmaxf(v.z, v.w));
    }
#pragma unroll
    for (int off = 32; off >= 1; off >>= 1)
        lm = fmaxf(lm, __shfl_xor(lm, off));
    if ((tid & 63) == 0) wred[tid >> 6] = lm;
    __syncthreads();
    const float M = fmaxf(fmaxf(wred[0], wred[1]), fmaxf(wred[2], wred[3]));

    const float ss = s_src[nbase + i0 + row];
    const float t0 = ss + M;
    const float m_i = fmaxf(t0, NEG_SLOPE * t0);   // exact row max of leaky logits

    float acc[16];
#pragma unroll
    for (int c = 0; c < 16; ++c) acc[c] = 0.f;
    float denom = 0.f;

    for (int jt = 0; jt < V_N / 128; ++jt) {
        __syncthreads();
        // stage h j-tile: 128 x 64 = 2048 float4, 8/thread, coalesced
#pragma unroll
        for (int t = 0; t < 8; ++t) {
            int f4 = tid + t * 256;
            float4 v = *reinterpret_cast<const float4*>(
                h + (nbase + (size_t)jt * 128) * H_D + (size_t)f4 * 4);
            *reinterpret_cast<float4*>(&hs[0][0] + (size_t)f4 * 4) = v;
        }
        __syncthreads();
#pragma unroll 4
        for (int j = 0; j < 128; ++j) {
            float x = ss + sd[jt * 128 + j];       // broadcast LDS read
            float e = fmaxf(x, NEG_SLOPE * x);     // leaky relu
            float w = __expf(e - m_i);
            denom += w;
            const float4* hr = reinterpret_cast<const float4*>(&hs[j][hq * 16]);
            float hv[16];
            *reinterpret_cast<float4*>(&hv[0])  = hr[0];  // broadcast reads
            *reinterpret_cast<float4*>(&hv[4])  = hr[1];
            *reinterpret_cast<float4*>(&hv[8])  = hr[2];
            *reinterpret_cast<float4*>(&hv[12]) = hr[3];
#pragma unroll
            for (int c = 0; c < 16; ++c) acc[c] += w * hv[c];
        }
    }

    const float inv = 1.0f / denom;
#pragma unroll
    for (int c4 = 0; c4 < 4; ++c4) {
        float4 v = make_float4(acc[c4 * 4 + 0] * inv, acc[c4 * 4 + 1] * inv,
                               acc[c4 * 4 + 2] * inv, acc[c4 * 4 + 3] * inv);
        *reinterpret_cast<float4*>(out + (nbase + i0 + row) * H_D + hq * 16 + c4 * 4) = v;
    }
}

extern "C" void kernel_launch(void* const* d_in, const int* in_sizes, int n_in,
                              void* d_out, int out_size, void* d_ws, size_t ws_size,
                              hipStream_t stream) {
    const float* feat = (const float*)d_in[0];  // (32,1024,128)
    const float* W    = (const float*)d_in[1];  // (64,128)
    const float* a    = (const float*)d_in[2];  // (1,128)
    float* out = (float*)d_out;                 // (32,1024,64)

    float* h     = (float*)d_ws;                // NV*64 floats = 8 MB
    float* s_src = h + (size_t)NV * H_D;        // NV floats
    float* s_dst = s_src + NV;                  // NV floats

    gat_h_kernel<<<NV / 64, 256, 0, stream>>>(feat, W, a, h, s_src, s_dst);
    gat_attn_kernel<<<N_G * (V_N / 64), 256, 0, stream>>>(h, s_src, s_dst, out);
}

// Round 4
// 112.314 us; speedup vs baseline: 1.4574x; 1.4574x over previous
//
#include <hip/hip_runtime.h>
#include <hip/hip_bf16.h>

#define NEG_SLOPE 0.01f

constexpr int N_G  = 32;    // graphs
constexpr int V_N  = 1024;  // nodes per graph
constexpr int F_IN = 128;
constexpr int H_D  = 64;
constexpr int NV   = N_G * V_N;  // 32768

typedef __attribute__((ext_vector_type(8))) short bf16x8;  // 8 bf16 (4 VGPRs)
typedef __attribute__((ext_vector_type(4))) float f32x4;   // MFMA C/D

// ---------------------------------------------------------------------------
// Kernel 1: h = features @ W^T (f32, exact logits path), writing:
//   hT   : per-graph transposed bf16 copy hT[g][c][j]  (PV B-operand)
//   s_src/s_dst : h @ a halves (f32, exact)
// Block: 64 rows, 256 threads; thread = (row=tid&63, hq=tid>>6) owns 16 cols.
// ---------------------------------------------------------------------------
__global__ __launch_bounds__(256) void gat_h_kernel(
    const float* __restrict__ feat,   // (NV, 128)
    const float* __restrict__ W,      // (64, 128)
    const float* __restrict__ a,      // (128)
    __hip_bfloat16* __restrict__ hT,  // (32, 64, 1024) bf16
    float* __restrict__ s_src,        // (NV)
    float* __restrict__ s_dst)        // (NV)
{
    __shared__ float Fs[64][65];     // +1 pad: Fs[row][k] reads 2-way (free)
    __shared__ float WsT[64][64];    // WsT[k][c]; reads are wave-uniform (broadcast)
    __shared__ float red[2][4][64];

    const int tid = threadIdx.x;
    const int row = tid & 63;
    const int hq  = tid >> 6;
    const int r0  = blockIdx.x * 64;

    float acc[16];
#pragma unroll
    for (int c = 0; c < 16; ++c) acc[c] = 0.f;

    for (int kh = 0; kh < 2; ++kh) {
        __syncthreads();
#pragma unroll
        for (int t = 0; t < 4; ++t) {
            int f4 = tid + t * 256;
            int rr = f4 >> 4;
            int kk = (f4 & 15) << 2;
            float4 v = *reinterpret_cast<const float4*>(
                feat + (size_t)(r0 + rr) * F_IN + kh * 64 + kk);
            Fs[rr][kk + 0] = v.x; Fs[rr][kk + 1] = v.y;
            Fs[rr][kk + 2] = v.z; Fs[rr][kk + 3] = v.w;
        }
#pragma unroll
        for (int t = 0; t < 4; ++t) {
            int f4 = tid + t * 256;
            int hh = f4 >> 4;
            int kk = (f4 & 15) << 2;
            float4 v = *reinterpret_cast<const float4*>(
                W + (size_t)hh * F_IN + kh * 64 + kk);
            WsT[kk + 0][hh] = v.x; WsT[kk + 1][hh] = v.y;
            WsT[kk + 2][hh] = v.z; WsT[kk + 3][hh] = v.w;
        }
        __syncthreads();
#pragma unroll 8
        for (int k = 0; k < 64; ++k) {
            float fv = Fs[row][k];
            const float4* wrow = reinterpret_cast<const float4*>(&WsT[k][hq * 16]);
            float wv[16];
            *reinterpret_cast<float4*>(&wv[0])  = wrow[0];
            *reinterpret_cast<float4*>(&wv[4])  = wrow[1];
            *reinterpret_cast<float4*>(&wv[8])  = wrow[2];
            *reinterpret_cast<float4*>(&wv[12]) = wrow[3];
#pragma unroll
            for (int c = 0; c < 16; ++c) acc[c] += fv * wv[c];
        }
    }

    // s_src / s_dst partials (exact f32 logits path)
    float ps = 0.f, pd = 0.f;
#pragma unroll
    for (int c = 0; c < 16; ++c) {
        ps += acc[c] * a[hq * 16 + c];
        pd += acc[c] * a[H_D + hq * 16 + c];
    }
    red[0][hq][row] = ps;
    red[1][hq][row] = pd;

    // transposed bf16 copy for the MFMA PV operand: hT[g][c][j]
    // lanes have consecutive row -> each store is a coalesced 128B wave-write
    {
        const int g    = r0 >> 10;
        const int rloc = (r0 & (V_N - 1)) + row;
        __hip_bfloat16* hTg = hT + (size_t)g * H_D * V_N;
#pragma unroll
        for (int c = 0; c < 16; ++c)
            hTg[(size_t)(hq * 16 + c) * V_N + rloc] = __float2bfloat16(acc[c]);
    }

    __syncthreads();
    if (tid < 64) {
        s_src[r0 + tid] = red[0][0][tid] + red[0][1][tid] + red[0][2][tid] + red[0][3][tid];
    } else if (tid < 128) {
        int r = tid - 64;
        s_dst[r0 + r] = red[1][0][r] + red[1][1][r] + red[1][2][r] + red[1][3][r];
    }
}

// ---------------------------------------------------------------------------
// Kernel 2: fused softmax + PV via MFMA.
// Exact row max via monotonicity of leakyrelu: m_i = leaky(ss_i + max_j sd_j).
// Block = 256 threads = 4 waves; wave w owns 16 rows (i0 + w*16 ..).
// Per k-step (K=32): lane (m=lane&15, kg=lane>>4) generates 8 P values
// (A-frag, rows=m, k=kg*8+r), loads 4 B-frags from hT (n=lane&15, same k-map
// -> any within-lane k-permutation cancels in the MFMA's Sum_k), and issues
// 4 PV MFMAs + 1 ones-MFMA for the denominator (layout-proof row sums; the
// same bf16 P feeds numerator & denominator so quantization largely divides out).
// ---------------------------------------------------------------------------
__global__ __launch_bounds__(256) void gat_attn_mfma(
    const __hip_bfloat16* __restrict__ hT, // (32, 64, 1024)
    const float* __restrict__ s_src,       // (NV)
    const float* __restrict__ s_dst,       // (NV)
    float* __restrict__ out)               // (NV, 64)
{
    __shared__ float sd[V_N];   // 4 KB
    __shared__ float wred[4];

    const int tid  = threadIdx.x;
    const int lane = tid & 63;
    const int wv   = tid >> 6;
    const int m    = lane & 15;   // A row / B col / D col
    const int kg   = lane >> 4;   // k-group
    const int n    = blockIdx.x >> 4;
    const int i0   = (blockIdx.x & 15) * 64;
    const size_t nbase = (size_t)n * V_N;

    // stage s_dst[n,:] + max
    float lm;
    {
        float4 v = *reinterpret_cast<const float4*>(s_dst + nbase + tid * 4);
        *reinterpret_cast<float4*>(&sd[tid * 4]) = v;
        lm = fmaxf(fmaxf(v.x, v.y), fmaxf(v.z, v.w));
    }
#pragma unroll
    for (int off = 32; off >= 1; off >>= 1)
        lm = fmaxf(lm, __shfl_xor(lm, off));
    if (lane == 0) wred[wv] = lm;

    const int row  = i0 + wv * 16 + m;
    const float ss = s_src[nbase + row];   // issue before barrier (hide latency)
    __syncthreads();
    const float M    = fmaxf(fmaxf(wred[0], wred[1]), fmaxf(wred[2], wred[3]));
    const float t0   = ss + M;
    const float negm = -fmaxf(t0, NEG_SLOPE * t0);  // exact -rowmax of leaky logits

    f32x4 accC[4];
    f32x4 accD = {0.f, 0.f, 0.f, 0.f};
#pragma unroll
    for (int t = 0; t < 4; ++t) accC[t] = (f32x4){0.f, 0.f, 0.f, 0.f};

    bf16x8 ones;
#pragma unroll
    for (int r = 0; r < 8; ++r) ones[r] = (short)0x3F80;  // 1.0 bf16

    const __hip_bfloat16* hTg = hT + (size_t)n * H_D * V_N;

    for (int jt = 0; jt < V_N / 32; ++jt) {
        // B-frags: B[k][n] = h[jt*32 + k][t*16 + n], 16B contiguous per lane (L2-hot)
        bf16x8 B[4];
#pragma unroll
        for (int t = 0; t < 4; ++t)
            B[t] = *reinterpret_cast<const bf16x8*>(
                hTg + (size_t)(t * 16 + m) * V_N + jt * 32 + kg * 8);

        // sd slice: lanes in a 16-group read identical 16B -> broadcast, free
        float p[8];
        *reinterpret_cast<float4*>(&p[0]) =
            *reinterpret_cast<const float4*>(&sd[jt * 32 + kg * 8]);
        *reinterpret_cast<float4*>(&p[4]) =
            *reinterpret_cast<const float4*>(&sd[jt * 32 + kg * 8 + 4]);

        // A-frag: P[m][k] = exp(leaky(ss + sd[k]) - m_i), bf16
        bf16x8 A;
#pragma unroll
        for (int r = 0; r < 8; ++r) {
            float tt = ss + p[r];
            float l  = fmaxf(tt, NEG_SLOPE * tt);
            float w  = __expf(l + negm);          // in (0, 1]
            A[r] = (short)__builtin_bit_cast(unsigned short, __float2bfloat16(w));
        }

        accD = __builtin_amdgcn_mfma_f32_16x16x32_bf16(A, ones, accD, 0, 0, 0);
#pragma unroll
        for (int t = 0; t < 4; ++t)
            accC[t] = __builtin_amdgcn_mfma_f32_16x16x32_bf16(A, B[t], accC[t], 0, 0, 0);
    }

    // epilogue: C/D rows = kg*4 + r, cols = t*16 + m; accD rows match accC rows
    float inv[4];
#pragma unroll
    for (int r = 0; r < 4; ++r) inv[r] = 1.0f / accD[r];
#pragma unroll
    for (int r = 0; r < 4; ++r) {
        const size_t ob = (nbase + i0 + wv * 16 + kg * 4 + r) * H_D;
#pragma unroll
        for (int t = 0; t < 4; ++t)
            out[ob + t * 16 + m] = accC[t][r] * inv[r];
    }
}

extern "C" void kernel_launch(void* const* d_in, const int* in_sizes, int n_in,
                              void* d_out, int out_size, void* d_ws, size_t ws_size,
                              hipStream_t stream) {
    const float* feat = (const float*)d_in[0];  // (32,1024,128)
    const float* W    = (const float*)d_in[1];  // (64,128)
    const float* a    = (const float*)d_in[2];  // (1,128)
    float* out = (float*)d_out;                 // (32,1024,64)

    __hip_bfloat16* hT = (__hip_bfloat16*)d_ws;          // NV*64 bf16 = 4 MB
    float* s_src = (float*)(hT + (size_t)NV * H_D);      // NV floats
    float* s_dst = s_src + NV;                           // NV floats

    gat_h_kernel<<<NV / 64, 256, 0, stream>>>(feat, W, a, hT, s_src, s_dst);
    gat_attn_mfma<<<N_G * (V_N / 64), 256, 0, stream>>>(hT, s_src, s_dst, out);
}

// Round 7
// 96.864 us; speedup vs baseline: 1.6899x; 1.1595x over previous
//
#include <hip/hip_runtime.h>
#include <hip/hip_bf16.h>

#define NEG_SLOPE 0.01f

constexpr int N_G  = 32;    // graphs
constexpr int V_N  = 1024;  // nodes per graph
constexpr int F_IN = 128;
constexpr int H_D  = 64;
constexpr int NV   = N_G * V_N;  // 32768

typedef __attribute__((ext_vector_type(8))) short bf16x8;  // 8 bf16 (4 VGPRs)
typedef __attribute__((ext_vector_type(4))) float f32x4;   // MFMA C/D

// hT layout (per graph): 16 tiles of 64 j x 64 c, 8KB each, elements in MFMA
// B-frag order: within tile, chunk chi = (t*2+kk)*64 + kg*16 + m  (t=c>>4,
// m=c&15, kk=(j>>5)&1, kg=(j>>3)&3), byte = chi*16 + (j&7)*2. Kernel 2 then
// reads B-frags at base + (t*2+kk)*1024 + lane*16 -- linear, conflict-free.

// ---------------------------------------------------------------------------
// Kernel 1: h = features @ W^T (f32 VALU, exact logits path), writing:
//   hT (frag-ordered bf16 tiles, see above), s_src/s_dst (f32, exact)
// ---------------------------------------------------------------------------
__global__ __launch_bounds__(256) void gat_h_kernel(
    const float* __restrict__ feat,   // (NV, 128)
    const float* __restrict__ W,      // (64, 128)
    const float* __restrict__ a,      // (128)
    __hip_bfloat16* __restrict__ hT,  // (32, 64, 1024) bf16, frag-ordered
    float* __restrict__ s_src,        // (NV)
    float* __restrict__ s_dst)        // (NV)
{
    __shared__ float Fs[64][65];     // +1 pad: Fs[row][k] reads 2-way (free)
    __shared__ float WsT[64][64];    // WsT[k][c]; reads wave-uniform broadcast
    __shared__ float red[2][4][64];

    const int tid = threadIdx.x;
    const int row = tid & 63;
    const int hq  = tid >> 6;
    const int r0  = blockIdx.x * 64;

    float acc[16];
#pragma unroll
    for (int c = 0; c < 16; ++c) acc[c] = 0.f;

    for (int kh = 0; kh < 2; ++kh) {
        __syncthreads();
#pragma unroll
        for (int t = 0; t < 4; ++t) {
            int f4 = tid + t * 256;
            int rr = f4 >> 4;
            int kk = (f4 & 15) << 2;
            float4 v = *reinterpret_cast<const float4*>(
                feat + (size_t)(r0 + rr) * F_IN + kh * 64 + kk);
            Fs[rr][kk + 0] = v.x; Fs[rr][kk + 1] = v.y;
            Fs[rr][kk + 2] = v.z; Fs[rr][kk + 3] = v.w;
        }
#pragma unroll
        for (int t = 0; t < 4; ++t) {
            int f4 = tid + t * 256;
            int hh = f4 >> 4;
            int kk = (f4 & 15) << 2;
            float4 v = *reinterpret_cast<const float4*>(
                W + (size_t)hh * F_IN + kh * 64 + kk);
            WsT[kk + 0][hh] = v.x; WsT[kk + 1][hh] = v.y;
            WsT[kk + 2][hh] = v.z; WsT[kk + 3][hh] = v.w;
        }
        __syncthreads();
#pragma unroll 8
        for (int k = 0; k < 64; ++k) {
            float fv = Fs[row][k];
            const float4* wrow = reinterpret_cast<const float4*>(&WsT[k][hq * 16]);
            float wv[16];
            *reinterpret_cast<float4*>(&wv[0])  = wrow[0];
            *reinterpret_cast<float4*>(&wv[4])  = wrow[1];
            *reinterpret_cast<float4*>(&wv[8])  = wrow[2];
            *reinterpret_cast<float4*>(&wv[12]) = wrow[3];
#pragma unroll
            for (int c = 0; c < 16; ++c) acc[c] += fv * wv[c];
        }
    }

    // s_src / s_dst partials (exact f32 logits path)
    float ps = 0.f, pd = 0.f;
#pragma unroll
    for (int c = 0; c < 16; ++c) {
        ps += acc[c] * a[hq * 16 + c];
        pd += acc[c] * a[H_D + hq * 16 + c];
    }
    red[0][hq][row] = ps;
    red[1][hq][row] = pd;

    // frag-ordered bf16 hT write: this block's 64 rows = exactly one j-tile
    {
        const int g   = r0 >> 10;
        const int rl  = (r0 & (V_N - 1)) + row;  // j within graph
        const int jt  = rl >> 6;
        const int j   = rl & 63;
        const int kk  = (j >> 5) & 1;
        const int kg  = (j >> 3) & 3;
        const int r   = j & 7;
        char* tile = (char*)(hT + (size_t)g * H_D * V_N) + (size_t)jt * 8192;
#pragma unroll
        for (int cc = 0; cc < 16; ++cc) {
            int byteoff = ((((hq * 2 + kk) * 64) + kg * 16 + cc) << 4) + (r << 1);
            *reinterpret_cast<__hip_bfloat16*>(tile + byteoff) = __float2bfloat16(acc[cc]);
        }
    }

    __syncthreads();
    if (tid < 64) {
        s_src[r0 + tid] = red[0][0][tid] + red[0][1][tid] + red[0][2][tid] + red[0][3][tid];
    } else if (tid < 128) {
        int r = tid - 64;
        s_dst[r0 + r] = red[1][0][r] + red[1][1][r] + red[1][2][r] + red[1][3][r];
    }
}

// ---------------------------------------------------------------------------
// Kernel 2: fused softmax + PV via MFMA, LDS-staged double-buffered B tiles.
// Exact row max via leakyrelu monotonicity. Block = 4 waves, 64 i-rows.
// Per 64-j stage: coalesced 32B/thread global load of the frag-ordered 8KB
// tile -> linear LDS write (0-conflict) -> B-frags at lane*16 (0-conflict).
// Denominator via ones-MFMA on the same bf16 P (quantization divides out).
// ---------------------------------------------------------------------------
__global__ __launch_bounds__(256) void gat_attn_mfma(
    const __hip_bfloat16* __restrict__ hT, // (32, 64, 1024) frag-ordered
    const float* __restrict__ s_src,       // (NV)
    const float* __restrict__ s_dst,       // (NV)
    float* __restrict__ out)               // (NV, 64)
{
    __shared__ float sd[V_N];   // 4 KB
    __shared__ float wred[4];
    __shared__ int4 hbuf[2][512];  // 2 x 8 KB, frag-ordered B tiles

    const int tid  = threadIdx.x;
    const int lane = tid & 63;
    const int wv   = tid >> 6;
    const int m    = lane & 15;   // A row / D col
    const int kg   = lane >> 4;   // k-group
    const int n    = blockIdx.x >> 4;
    const int i0   = (blockIdx.x & 15) * 64;
    const size_t nbase = (size_t)n * V_N;

    const char* hTg = (const char*)(hT + (size_t)n * H_D * V_N);

    // stage s_dst[n,:] + max
    float lm;
    {
        float4 v = *reinterpret_cast<const float4*>(s_dst + nbase + tid * 4);
        *reinterpret_cast<float4*>(&sd[tid * 4]) = v;
        lm = fmaxf(fmaxf(v.x, v.y), fmaxf(v.z, v.w));
    }
#pragma unroll
    for (int off = 32; off >= 1; off >>= 1)
        lm = fmaxf(lm, __shfl_xor(lm, off));
    if (lane == 0) wred[wv] = lm;

    const int row  = i0 + wv * 16 + m;
    const float ss = s_src[nbase + row];

    // prologue: stage tile 0 (coalesced 32B/thread, linear LDS)
    {
        int4 s0 = *reinterpret_cast<const int4*>(hTg + tid * 32);
        int4 s1 = *reinterpret_cast<const int4*>(hTg + tid * 32 + 16);
        hbuf[0][tid * 2]     = s0;
        hbuf[0][tid * 2 + 1] = s1;
    }
    __syncthreads();

    const float M    = fmaxf(fmaxf(wred[0], wred[1]), fmaxf(wred[2], wred[3]));
    const float t0   = ss + M;
    const float negm = -fmaxf(t0, NEG_SLOPE * t0);  // exact -rowmax of leaky logits

    f32x4 accC[4];
    f32x4 accD = {0.f, 0.f, 0.f, 0.f};
#pragma unroll
    for (int t = 0; t < 4; ++t) accC[t] = (f32x4){0.f, 0.f, 0.f, 0.f};

    bf16x8 ones;
#pragma unroll
    for (int r = 0; r < 8; ++r) ones[r] = (short)0x3F80;  // 1.0 bf16

    int cur = 0;
    for (int jt = 0; jt < V_N / 64; ++jt) {
        // issue next tile's loads early (L2 latency hides under compute)
        int4 n0, n1;
        if (jt < V_N / 64 - 1) {
            const char* g = hTg + (size_t)(jt + 1) * 8192 + tid * 32;
            n0 = *reinterpret_cast<const int4*>(g);
            n1 = *reinterpret_cast<const int4*>(g + 16);
        }

        const char* bb = (const char*)&hbuf[cur][0];
#pragma unroll
        for (int kk = 0; kk < 2; ++kk) {
            // sd slice: 16-lane groups read identical 16B -> broadcast, free
            float p[8];
            *reinterpret_cast<float4*>(&p[0]) =
                *reinterpret_cast<const float4*>(&sd[jt * 64 + kk * 32 + kg * 8]);
            *reinterpret_cast<float4*>(&p[4]) =
                *reinterpret_cast<const float4*>(&sd[jt * 64 + kk * 32 + kg * 8 + 4]);

            // A-frag: P[m][k] = exp(leaky(ss + sd[k]) - m_i), bf16
            bf16x8 A;
#pragma unroll
            for (int r = 0; r < 8; ++r) {
                float tt = ss + p[r];
                float l  = fmaxf(tt, NEG_SLOPE * tt);
                float w  = __expf(l + negm);          // in (0, 1]
                A[r] = (short)__builtin_bit_cast(unsigned short, __float2bfloat16(w));
            }

            accD = __builtin_amdgcn_mfma_f32_16x16x32_bf16(A, ones, accD, 0, 0, 0);
#pragma unroll
            for (int t = 0; t < 4; ++t) {
                bf16x8 B = *reinterpret_cast<const bf16x8*>(
                    bb + (t * 2 + kk) * 1024 + lane * 16);
                accC[t] = __builtin_amdgcn_mfma_f32_16x16x32_bf16(A, B, accC[t], 0, 0, 0);
            }
        }

        // write-late: land next tile in the other buffer, one barrier/stage
        if (jt < V_N / 64 - 1) {
            hbuf[cur ^ 1][tid * 2]     = n0;
            hbuf[cur ^ 1][tid * 2 + 1] = n1;
        }
        __syncthreads();
        cur ^= 1;
    }

    // epilogue: C/D rows = kg*4 + r, cols = t*16 + m
    float inv[4];
#pragma unroll
    for (int r = 0; r < 4; ++r) inv[r] = 1.0f / accD[r];
#pragma unroll
    for (int r = 0; r < 4; ++r) {
        const size_t ob = (nbase + i0 + wv * 16 + kg * 4 + r) * H_D;
#pragma unroll
        for (int t = 0; t < 4; ++t)
            out[ob + t * 16 + m] = accC[t][r] * inv[r];
    }
}

extern "C" void kernel_launch(void* const* d_in, const int* in_sizes, int n_in,
                              void* d_out, int out_size, void* d_ws, size_t ws_size,
                              hipStream_t stream) {
    const float* feat = (const float*)d_in[0];  // (32,1024,128)
    const float* W    = (const float*)d_in[1];  // (64,128)
    const float* a    = (const float*)d_in[2];  // (1,128)
    float* out = (float*)d_out;                 // (32,1024,64)

    __hip_bfloat16* hT = (__hip_bfloat16*)d_ws;          // NV*64 bf16 = 4 MB
    float* s_src = (float*)(hT + (size_t)NV * H_D);      // NV floats
    float* s_dst = s_src + NV;                           // NV floats

    gat_h_kernel<<<NV / 64, 256, 0, stream>>>(feat, W, a, hT, s_src, s_dst);
    gat_attn_mfma<<<N_G * (V_N / 64), 256, 0, stream>>>(hT, s_src, s_dst, out);
}

// Round 9
// 89.743 us; speedup vs baseline: 1.8240x; 1.0793x over previous
//
#include <hip/hip_runtime.h>
#include <hip/hip_bf16.h>

#define NEG_SLOPE 0.01f

constexpr int N_G  = 32;    // graphs
constexpr int V_N  = 1024;  // nodes per graph
constexpr int F_IN = 128;
constexpr int H_D  = 64;
constexpr int NV   = N_G * V_N;  // 32768

typedef __attribute__((ext_vector_type(8))) short bf16x8;  // 8 bf16 (4 VGPRs)
typedef __attribute__((ext_vector_type(4))) float f32x4;   // MFMA C/D

__device__ __forceinline__ float bf16bits_to_f32(unsigned short u) {
    unsigned int x = ((unsigned int)u) << 16;
    return __builtin_bit_cast(float, x);
}
__device__ __forceinline__ unsigned short f32_to_bf16bits(float f) {
    return __builtin_bit_cast(unsigned short, __float2bfloat16(f));
}

// hT layout (per graph): 16 tiles of 64 j x 64 c, 8KB each, elements in MFMA
// B-frag order: within tile, chunk chi = (t*2+kk)*64 + kg*16 + m  (t=c>>4,
// m=c&15, kk=(j>>5)&1, kg=(j>>3)&3), byte = chi*16 + (j&7)*2. Kernel 2
// reads B-frags at base + (t*2+kk)*1024 + lane*16 -- linear, conflict-free.

// ---------------------------------------------------------------------------
// Kernel 1: h = features @ W^T via bf16x3 split-precision MFMA (f32-accurate):
//   f32 = hi(bf16) + lo(bf16);  h ~= Ah*Bh + Ah*Bl + Al*Bh  (lo*lo ~ 2^-18 dropped)
// Outputs: hT (frag-ordered bf16), s_src/s_dst (f32 from f32 accumulators).
// Block: 64 rows, 256 threads = 4 waves; wave w owns rows w*16..w*16+15,
// all 64 cols (4 n-tiles), K=128 in 4 k-steps of 32.
// Operand lane-maps are exactly those validated end-to-end by kernel 2:
//   A: row=lane&15, k=(lane>>4)*8+r ; B: col=lane&15, same k-map ;
//   D: col=lane&15, row=(lane>>4)*4+reg.
// ---------------------------------------------------------------------------
__global__ __launch_bounds__(256) void gat_h_mfma(
    const float* __restrict__ feat,   // (NV, 128)
    const float* __restrict__ W,      // (64, 128)
    const float* __restrict__ a,      // (128)
    __hip_bfloat16* __restrict__ hT,  // (32, 64, 1024) bf16, frag-ordered
    float* __restrict__ s_src,        // (NV)
    float* __restrict__ s_dst)        // (NV)
{
    __shared__ __align__(16) float Fs[64][132];          // 33.8KB feat tile (padded)
    __shared__ __align__(16) unsigned short Wf[16384];   // 32KB frag-ordered W hi/lo
    // Wf chunk layout: byte = ((ks*4+t)*2+hl)*1024 + (kg*16+n')*16 + r*2

    const int tid  = threadIdx.x;
    const int lane = tid & 63;
    const int w    = tid >> 6;
    const int mb   = lane & 15;   // A-row / B-col / D-col field
    const int kg   = lane >> 4;   // k-group
    const int r0   = blockIdx.x * 64;

    // ---- stage feat tile (64 x 128 f32), coalesced float4 ----
#pragma unroll
    for (int t = 0; t < 8; ++t) {
        int f4  = tid + t * 256;
        int row = f4 >> 5;
        int c4  = (f4 & 31) << 2;
        float4 v = *reinterpret_cast<const float4*>(
            feat + (size_t)(r0 + row) * F_IN + c4);
        *reinterpret_cast<float4*>(&Fs[row][c4]) = v;
    }
    // ---- stage W as frag-ordered bf16 hi/lo ----
#pragma unroll
    for (int t = 0; t < 8; ++t) {
        int f4 = tid + t * 256;
        int n  = f4 >> 5;
        int k4 = (f4 & 31) << 2;          // k4 % 4 == 0, so all 4 elems share kg
        float4 v = *reinterpret_cast<const float4*>(W + (size_t)n * F_IN + k4);
        int ks  = k4 >> 5;
        int kgw = (k4 >> 3) & 3;
        int rr  = k4 & 7;                  // 0 or 4
        int tt  = n >> 4, nn = n & 15;
        float fv[4] = {v.x, v.y, v.z, v.w};
        unsigned long long ph = 0, pl = 0;
#pragma unroll
        for (int e = 0; e < 4; ++e) {
            unsigned short hb = f32_to_bf16bits(fv[e]);
            unsigned short lb = f32_to_bf16bits(fv[e] - bf16bits_to_f32(hb));
            ph |= ((unsigned long long)hb) << (16 * e);
            pl |= ((unsigned long long)lb) << (16 * e);
        }
        char* base = (char*)Wf;
        int chunk  = (ks * 4 + tt) * 2;
        int off    = (kgw * 16 + nn) * 16 + rr * 2;   // 8B-aligned
        *reinterpret_cast<unsigned long long*>(base + chunk * 1024 + off)       = ph;
        *reinterpret_cast<unsigned long long*>(base + (chunk + 1) * 1024 + off) = pl;
    }
    __syncthreads();

    f32x4 acc[4];
#pragma unroll
    for (int t = 0; t < 4; ++t) acc[t] = (f32x4){0.f, 0.f, 0.f, 0.f};

    const char* wfb = (const char*)Wf;
#pragma unroll
    for (int ks = 0; ks < 4; ++ks) {
        // A-frags: 2x ds_read_b128 (row-pad 132 -> bank spans at b128 floor)
        float af[8];
        *reinterpret_cast<float4*>(&af[0]) =
            *reinterpret_cast<const float4*>(&Fs[w * 16 + mb][ks * 32 + kg * 8]);
        *reinterpret_cast<float4*>(&af[4]) =
            *reinterpret_cast<const float4*>(&Fs[w * 16 + mb][ks * 32 + kg * 8 + 4]);
        bf16x8 Ah, Al;
#pragma unroll
        for (int e = 0; e < 8; ++e) {
            unsigned short hb = f32_to_bf16bits(af[e]);
            Ah[e] = (short)hb;
            Al[e] = (short)f32_to_bf16bits(af[e] - bf16bits_to_f32(hb));
        }
#pragma unroll
        for (int t = 0; t < 4; ++t) {
            bf16x8 Bh = *reinterpret_cast<const bf16x8*>(
                wfb + (size_t)((ks * 4 + t) * 2) * 1024 + lane * 16);
            bf16x8 Bl = *reinterpret_cast<const bf16x8*>(
                wfb + (size_t)((ks * 4 + t) * 2 + 1) * 1024 + lane * 16);
            acc[t] = __builtin_amdgcn_mfma_f32_16x16x32_bf16(Al, Bh, acc[t], 0, 0, 0);
            acc[t] = __builtin_amdgcn_mfma_f32_16x16x32_bf16(Ah, Bl, acc[t], 0, 0, 0);
            acc[t] = __builtin_amdgcn_mfma_f32_16x16x32_bf16(Ah, Bh, acc[t], 0, 0, 0);
        }
    }

    // ---- s_src / s_dst from f32 accumulators (exact logits path) ----
    float asrc[4], adst[4];
#pragma unroll
    for (int t = 0; t < 4; ++t) {
        asrc[t] = a[t * 16 + mb];
        adst[t] = a[H_D + t * 16 + mb];
    }
    float ps[4], pd[4];
#pragma unroll
    for (int reg = 0; reg < 4; ++reg) {
        ps[reg] = acc[0][reg] * asrc[0] + acc[1][reg] * asrc[1]
                + acc[2][reg] * asrc[2] + acc[3][reg] * asrc[3];
        pd[reg] = acc[0][reg] * adst[0] + acc[1][reg] * adst[1]
                + acc[2][reg] * adst[2] + acc[3][reg] * adst[3];
    }
#pragma unroll
    for (int off = 1; off < 16; off <<= 1) {
#pragma unroll
        for (int reg = 0; reg < 4; ++reg) {
            ps[reg] += __shfl_xor(ps[reg], off);
            pd[reg] += __shfl_xor(pd[reg], off);
        }
    }
    if (mb == 0) {
#pragma unroll
        for (int reg = 0; reg < 4; ++reg) {
            int j = w * 16 + kg * 4 + reg;   // D row
            s_src[r0 + j] = ps[reg];
            s_dst[r0 + j] = pd[reg];
        }
    }

    // ---- hT epilogue: LDS transpose -> coalesced frag-ordered bf16 stores ----
    __syncthreads();   // all waves done reading Fs
    float (*FsT)[65] = reinterpret_cast<float(*)[65]>(&Fs[0][0]);  // 16.6KB, aliases Fs
#pragma unroll
    for (int t = 0; t < 4; ++t)
#pragma unroll
        for (int reg = 0; reg < 4; ++reg)
            FsT[w * 16 + kg * 4 + reg][t * 16 + mb] = acc[t][reg];
    __syncthreads();

    const int g  = r0 >> 10;
    const int jt = (r0 & (V_N - 1)) >> 6;
    char* tile = (char*)(hT + (size_t)g * H_D * V_N) + (size_t)jt * 8192;
#pragma unroll
    for (int ch = 0; ch < 2; ++ch) {
        int chi = tid * 2 + ch;                 // chunk index 0..511
        int tp  = chi >> 7;
        int kk  = (chi >> 6) & 1;
        int kgp = (chi >> 4) & 3;
        int mp  = chi & 15;
        int c   = tp * 16 + mp;
        int jb  = kk * 32 + kgp * 8;
        unsigned short outp[8];
#pragma unroll
        for (int rr = 0; rr < 8; ++rr) outp[rr] = f32_to_bf16bits(FsT[jb + rr][c]);
        *reinterpret_cast<int4*>(tile + (size_t)chi * 16) =
            *reinterpret_cast<const int4*>(outp);   // 16B, consecutive tid -> coalesced
    }
}

// ---------------------------------------------------------------------------
// Kernel 2: fused softmax + PV via MFMA, LDS-staged double-buffered B tiles.
// (byte-identical to round 7 -- single-variable experiment)
// ---------------------------------------------------------------------------
__global__ __launch_bounds__(256) void gat_attn_mfma(
    const __hip_bfloat16* __restrict__ hT, // (32, 64, 1024) frag-ordered
    const float* __restrict__ s_src,       // (NV)
    const float* __restrict__ s_dst,       // (NV)
    float* __restrict__ out)               // (NV, 64)
{
    __shared__ float sd[V_N];   // 4 KB
    __shared__ float wred[4];
    __shared__ int4 hbuf[2][512];  // 2 x 8 KB, frag-ordered B tiles

    const int tid  = threadIdx.x;
    const int lane = tid & 63;
    const int wv   = tid >> 6;
    const int m    = lane & 15;   // A row / D col
    const int kg   = lane >> 4;   // k-group
    const int n    = blockIdx.x >> 4;
    const int i0   = (blockIdx.x & 15) * 64;
    const size_t nbase = (size_t)n * V_N;

    const char* hTg = (const char*)(hT + (size_t)n * H_D * V_N);

    // stage s_dst[n,:] + max
    float lm;
    {
        float4 v = *reinterpret_cast<const float4*>(s_dst + nbase + tid * 4);
        *reinterpret_cast<float4*>(&sd[tid * 4]) = v;
        lm = fmaxf(fmaxf(v.x, v.y), fmaxf(v.z, v.w));
    }
#pragma unroll
    for (int off = 32; off >= 1; off >>= 1)
        lm = fmaxf(lm, __shfl_xor(lm, off));
    if (lane == 0) wred[wv] = lm;

    const int row  = i0 + wv * 16 + m;
    const float ss = s_src[nbase + row];

    // prologue: stage tile 0 (coalesced 32B/thread, linear LDS)
    {
        int4 s0 = *reinterpret_cast<const int4*>(hTg + tid * 32);
        int4 s1 = *reinterpret_cast<const int4*>(hTg + tid * 32 + 16);
        hbuf[0][tid * 2]     = s0;
        hbuf[0][tid * 2 + 1] = s1;
    }
    __syncthreads();

    const float M    = fmaxf(fmaxf(wred[0], wred[1]), fmaxf(wred[2], wred[3]));
    const float t0   = ss + M;
    const float negm = -fmaxf(t0, NEG_SLOPE * t0);  // exact -rowmax of leaky logits

    f32x4 accC[4];
    f32x4 accD = {0.f, 0.f, 0.f, 0.f};
#pragma unroll
    for (int t = 0; t < 4; ++t) accC[t] = (f32x4){0.f, 0.f, 0.f, 0.f};

    bf16x8 ones;
#pragma unroll
    for (int r = 0; r < 8; ++r) ones[r] = (short)0x3F80;  // 1.0 bf16

    int cur = 0;
    for (int jt = 0; jt < V_N / 64; ++jt) {
        // issue next tile's loads early (L2 latency hides under compute)
        int4 n0, n1;
        if (jt < V_N / 64 - 1) {
            const char* g = hTg + (size_t)(jt + 1) * 8192 + tid * 32;
            n0 = *reinterpret_cast<const int4*>(g);
            n1 = *reinterpret_cast<const int4*>(g + 16);
        }

        const char* bb = (const char*)&hbuf[cur][0];
#pragma unroll
        for (int kk = 0; kk < 2; ++kk) {
            // sd slice: 16-lane groups read identical 16B -> broadcast, free
            float p[8];
            *reinterpret_cast<float4*>(&p[0]) =
                *reinterpret_cast<const float4*>(&sd[jt * 64 + kk * 32 + kg * 8]);
            *reinterpret_cast<float4*>(&p[4]) =
                *reinterpret_cast<const float4*>(&sd[jt * 64 + kk * 32 + kg * 8 + 4]);

            // A-frag: P[m][k] = exp(leaky(ss + sd[k]) - m_i), bf16
            bf16x8 A;
#pragma unroll
            for (int r = 0; r < 8; ++r) {
                float tt = ss + p[r];
                float l  = fmaxf(tt, NEG_SLOPE * tt);
                float w  = __expf(l + negm);          // in (0, 1]
                A[r] = (short)__builtin_bit_cast(unsigned short, __float2bfloat16(w));
            }

            accD = __builtin_amdgcn_mfma_f32_16x16x32_bf16(A, ones, accD, 0, 0, 0);
#pragma unroll
            for (int t = 0; t < 4; ++t) {
                bf16x8 B = *reinterpret_cast<const bf16x8*>(
                    bb + (t * 2 + kk) * 1024 + lane * 16);
                accC[t] = __builtin_amdgcn_mfma_f32_16x16x32_bf16(A, B, accC[t], 0, 0, 0);
            }
        }

        // write-late: land next tile in the other buffer, one barrier/stage
        if (jt < V_N / 64 - 1) {
            hbuf[cur ^ 1][tid * 2]     = n0;
            hbuf[cur ^ 1][tid * 2 + 1] = n1;
        }
        __syncthreads();
        cur ^= 1;
    }

    // epilogue: C/D rows = kg*4 + r, cols = t*16 + m
    float inv[4];
#pragma unroll
    for (int r = 0; r < 4; ++r) inv[r] = 1.0f / accD[r];
#pragma unroll
    for (int r = 0; r < 4; ++r) {
        const size_t ob = (nbase + i0 + wv * 16 + kg * 4 + r) * H_D;
#pragma unroll
        for (int t = 0; t < 4; ++t)
            out[ob + t * 16 + m] = accC[t][r] * inv[r];
    }
}

extern "C" void kernel_launch(void* const* d_in, const int* in_sizes, int n_in,
                              void* d_out, int out_size, void* d_ws, size_t ws_size,
                              hipStream_t stream) {
    const float* feat = (const float*)d_in[0];  // (32,1024,128)
    const float* W    = (const float*)d_in[1];  // (64,128)
    const float* a    = (const float*)d_in[2];  // (1,128)
    float* out = (float*)d_out;                 // (32,1024,64)

    __hip_bfloat16* hT = (__hip_bfloat16*)d_ws;          // NV*64 bf16 = 4 MB
    float* s_src = (float*)(hT + (size_t)NV * H_D);      // NV floats
    float* s_dst = s_src + NV;                           // NV floats

    gat_h_mfma<<<NV / 64, 256, 0, stream>>>(feat, W, a, hT, s_src, s_dst);
    gat_attn_mfma<<<N_G * (V_N / 64), 256, 0, stream>>>(hT, s_src, s_dst, out);
}

// Round 11
// 88.307 us; speedup vs baseline: 1.8537x; 1.0163x over previous
//
#include <hip/hip_runtime.h>
#include <hip/hip_bf16.h>

#define NEG_SLOPE 0.01f

constexpr int N_G  = 32;    // graphs
constexpr int V_N  = 1024;  // nodes per graph
constexpr int F_IN = 128;
constexpr int H_D  = 64;
constexpr int NV   = N_G * V_N;  // 32768

typedef __attribute__((ext_vector_type(8))) short bf16x8;  // 8 bf16 (4 VGPRs)
typedef __attribute__((ext_vector_type(4))) float f32x4;   // MFMA C/D

__device__ __forceinline__ float bf16bits_to_f32(unsigned short u) {
    unsigned int x = ((unsigned int)u) << 16;
    return __builtin_bit_cast(float, x);
}
__device__ __forceinline__ unsigned short f32_to_bf16bits(float f) {
    return __builtin_bit_cast(unsigned short, __float2bfloat16(f));
}

// hT layout (per graph): 16 tiles of 64 j x 64 c, 8KB each, elements in MFMA
// B-frag order: within tile, chunk chi = (t*2+kk)*64 + kg*16 + m  (t=c>>4,
// m=c&15, kk=(j>>5)&1, kg=(j>>3)&3), byte = chi*16 + (j&7)*2. Kernel 2
// reads B-frags at base + (t*2+kk)*1024 + lane*16 -- linear, conflict-free.

// ---------------------------------------------------------------------------
// Kernel 1: h = features @ W^T via bf16x3 split-precision MFMA (f32-accurate).
// (byte-identical to round 9 -- single-variable experiment on kernel 2)
// ---------------------------------------------------------------------------
__global__ __launch_bounds__(256) void gat_h_mfma(
    const float* __restrict__ feat,   // (NV, 128)
    const float* __restrict__ W,      // (64, 128)
    const float* __restrict__ a,      // (128)
    __hip_bfloat16* __restrict__ hT,  // (32, 64, 1024) bf16, frag-ordered
    float* __restrict__ s_src,        // (NV)
    float* __restrict__ s_dst)        // (NV)
{
    __shared__ __align__(16) float Fs[64][132];          // 33.8KB feat tile (padded)
    __shared__ __align__(16) unsigned short Wf[16384];   // 32KB frag-ordered W hi/lo

    const int tid  = threadIdx.x;
    const int lane = tid & 63;
    const int w    = tid >> 6;
    const int mb   = lane & 15;
    const int kg   = lane >> 4;
    const int r0   = blockIdx.x * 64;

#pragma unroll
    for (int t = 0; t < 8; ++t) {
        int f4  = tid + t * 256;
        int row = f4 >> 5;
        int c4  = (f4 & 31) << 2;
        float4 v = *reinterpret_cast<const float4*>(
            feat + (size_t)(r0 + row) * F_IN + c4);
        *reinterpret_cast<float4*>(&Fs[row][c4]) = v;
    }
#pragma unroll
    for (int t = 0; t < 8; ++t) {
        int f4 = tid + t * 256;
        int n  = f4 >> 5;
        int k4 = (f4 & 31) << 2;
        float4 v = *reinterpret_cast<const float4*>(W + (size_t)n * F_IN + k4);
        int ks  = k4 >> 5;
        int kgw = (k4 >> 3) & 3;
        int rr  = k4 & 7;
        int tt  = n >> 4, nn = n & 15;
        float fv[4] = {v.x, v.y, v.z, v.w};
        unsigned long long ph = 0, pl = 0;
#pragma unroll
        for (int e = 0; e < 4; ++e) {
            unsigned short hb = f32_to_bf16bits(fv[e]);
            unsigned short lb = f32_to_bf16bits(fv[e] - bf16bits_to_f32(hb));
            ph |= ((unsigned long long)hb) << (16 * e);
            pl |= ((unsigned long long)lb) << (16 * e);
        }
        char* base = (char*)Wf;
        int chunk  = (ks * 4 + tt) * 2;
        int off    = (kgw * 16 + nn) * 16 + rr * 2;
        *reinterpret_cast<unsigned long long*>(base + chunk * 1024 + off)       = ph;
        *reinterpret_cast<unsigned long long*>(base + (chunk + 1) * 1024 + off) = pl;
    }
    __syncthreads();

    f32x4 acc[4];
#pragma unroll
    for (int t = 0; t < 4; ++t) acc[t] = (f32x4){0.f, 0.f, 0.f, 0.f};

    const char* wfb = (const char*)Wf;
#pragma unroll
    for (int ks = 0; ks < 4; ++ks) {
        float af[8];
        *reinterpret_cast<float4*>(&af[0]) =
            *reinterpret_cast<const float4*>(&Fs[w * 16 + mb][ks * 32 + kg * 8]);
        *reinterpret_cast<float4*>(&af[4]) =
            *reinterpret_cast<const float4*>(&Fs[w * 16 + mb][ks * 32 + kg * 8 + 4]);
        bf16x8 Ah, Al;
#pragma unroll
        for (int e = 0; e < 8; ++e) {
            unsigned short hb = f32_to_bf16bits(af[e]);
            Ah[e] = (short)hb;
            Al[e] = (short)f32_to_bf16bits(af[e] - bf16bits_to_f32(hb));
        }
#pragma unroll
        for (int t = 0; t < 4; ++t) {
            bf16x8 Bh = *reinterpret_cast<const bf16x8*>(
                wfb + (size_t)((ks * 4 + t) * 2) * 1024 + lane * 16);
            bf16x8 Bl = *reinterpret_cast<const bf16x8*>(
                wfb + (size_t)((ks * 4 + t) * 2 + 1) * 1024 + lane * 16);
            acc[t] = __builtin_amdgcn_mfma_f32_16x16x32_bf16(Al, Bh, acc[t], 0, 0, 0);
            acc[t] = __builtin_amdgcn_mfma_f32_16x16x32_bf16(Ah, Bl, acc[t], 0, 0, 0);
            acc[t] = __builtin_amdgcn_mfma_f32_16x16x32_bf16(Ah, Bh, acc[t], 0, 0, 0);
        }
    }

    float asrc[4], adst[4];
#pragma unroll
    for (int t = 0; t < 4; ++t) {
        asrc[t] = a[t * 16 + mb];
        adst[t] = a[H_D + t * 16 + mb];
    }
    float ps[4], pd[4];
#pragma unroll
    for (int reg = 0; reg < 4; ++reg) {
        ps[reg] = acc[0][reg] * asrc[0] + acc[1][reg] * asrc[1]
                + acc[2][reg] * asrc[2] + acc[3][reg] * asrc[3];
        pd[reg] = acc[0][reg] * adst[0] + acc[1][reg] * adst[1]
                + acc[2][reg] * adst[2] + acc[3][reg] * adst[3];
    }
#pragma unroll
    for (int off = 1; off < 16; off <<= 1) {
#pragma unroll
        for (int reg = 0; reg < 4; ++reg) {
            ps[reg] += __shfl_xor(ps[reg], off);
            pd[reg] += __shfl_xor(pd[reg], off);
        }
    }
    if (mb == 0) {
#pragma unroll
        for (int reg = 0; reg < 4; ++reg) {
            int j = w * 16 + kg * 4 + reg;
            s_src[r0 + j] = ps[reg];
            s_dst[r0 + j] = pd[reg];
        }
    }

    __syncthreads();
    float (*FsT)[65] = reinterpret_cast<float(*)[65]>(&Fs[0][0]);
#pragma unroll
    for (int t = 0; t < 4; ++t)
#pragma unroll
        for (int reg = 0; reg < 4; ++reg)
            FsT[w * 16 + kg * 4 + reg][t * 16 + mb] = acc[t][reg];
    __syncthreads();

    const int g  = r0 >> 10;
    const int jt = (r0 & (V_N - 1)) >> 6;
    char* tile = (char*)(hT + (size_t)g * H_D * V_N) + (size_t)jt * 8192;
#pragma unroll
    for (int ch = 0; ch < 2; ++ch) {
        int chi = tid * 2 + ch;
        int tp  = chi >> 7;
        int kk  = (chi >> 6) & 1;
        int kgp = (chi >> 4) & 3;
        int mp  = chi & 15;
        int c   = tp * 16 + mp;
        int jb  = kk * 32 + kgp * 8;
        unsigned short outp[8];
#pragma unroll
        for (int rr = 0; rr < 8; ++rr) outp[rr] = f32_to_bf16bits(FsT[jb + rr][c]);
        *reinterpret_cast<int4*>(tile + (size_t)chi * 16) =
            *reinterpret_cast<const int4*>(outp);
    }
}

// ---------------------------------------------------------------------------
// Kernel 2 v2: fused softmax + PV via MFMA, j-split across wave-pairs.
// Block = 32 i-rows, 4 waves: rowhalf=wv&1 (rows i0+rowhalf*16+m),
// jhalf=wv>>1 (even/odd 64-j tiles, 8 each). Grid 1024 -> 4 blocks/CU,
// 16 waves/CU (2x round-9 occupancy; halves each wave's serial chain).
// Per step: stage tiles 2s+2,2s+3 (issue-early/write-late), compute tile
// 2s+jhalf from LDS. End: jhalf=1 partials (num+den) combined via LDS.
// ---------------------------------------------------------------------------
__global__ __launch_bounds__(256) void gat_attn_mfma(
    const __hip_bfloat16* __restrict__ hT, // (32, 64, 1024) frag-ordered
    const float* __restrict__ s_src,       // (NV)
    const float* __restrict__ s_dst,       // (NV)
    float* __restrict__ out)               // (NV, 64)
{
    __shared__ float sd[V_N];   // 4 KB
    __shared__ float wred[4];
    __shared__ __align__(16) int4 hbuf[2][2][512];  // [buf][jpar][...] 32 KB

    const int tid   = threadIdx.x;
    const int lane  = tid & 63;
    const int wv    = tid >> 6;
    const int rowhalf = wv & 1;
    const int jhalf   = wv >> 1;
    const int m     = lane & 15;   // A row (=P row) / D col
    const int kg    = lane >> 4;   // k-group
    const int n     = blockIdx.x >> 5;
    const int i0    = (blockIdx.x & 31) * 32;
    const size_t nbase = (size_t)n * V_N;

    const char* hTg = (const char*)(hT + (size_t)n * H_D * V_N);

    // stage s_dst[n,:] + max
    float lm;
    {
        float4 v = *reinterpret_cast<const float4*>(s_dst + nbase + tid * 4);
        *reinterpret_cast<float4*>(&sd[tid * 4]) = v;
        lm = fmaxf(fmaxf(v.x, v.y), fmaxf(v.z, v.w));
    }
#pragma unroll
    for (int off = 32; off >= 1; off >>= 1)
        lm = fmaxf(lm, __shfl_xor(lm, off));
    if (lane == 0) wred[wv] = lm;

    const float ss = s_src[nbase + i0 + rowhalf * 16 + m];

    // prologue: stage tiles 0 and 1 into buf 0 (coalesced 32B/thread/tile)
#pragma unroll
    for (int par = 0; par < 2; ++par) {
        const char* g = hTg + (size_t)par * 8192 + tid * 32;
        hbuf[0][par][tid * 2]     = *reinterpret_cast<const int4*>(g);
        hbuf[0][par][tid * 2 + 1] = *reinterpret_cast<const int4*>(g + 16);
    }
    __syncthreads();

    const float M    = fmaxf(fmaxf(wred[0], wred[1]), fmaxf(wred[2], wred[3]));
    const float t0   = ss + M;
    const float negm = -fmaxf(t0, NEG_SLOPE * t0);  // exact -rowmax of leaky logits

    f32x4 accC[4];
    f32x4 accD = {0.f, 0.f, 0.f, 0.f};
#pragma unroll
    for (int t = 0; t < 4; ++t) accC[t] = (f32x4){0.f, 0.f, 0.f, 0.f};

    bf16x8 ones;
#pragma unroll
    for (int r = 0; r < 8; ++r) ones[r] = (short)0x3F80;  // 1.0 bf16

    for (int s = 0; s < 8; ++s) {
        // issue next step's 2 tiles early (L2 latency hides under compute)
        int4 n00, n01, n10, n11;
        if (s < 7) {
            const char* g0 = hTg + (size_t)(2 * s + 2) * 8192 + tid * 32;
            const char* g1 = hTg + (size_t)(2 * s + 3) * 8192 + tid * 32;
            n00 = *reinterpret_cast<const int4*>(g0);
            n01 = *reinterpret_cast<const int4*>(g0 + 16);
            n10 = *reinterpret_cast<const int4*>(g1);
            n11 = *reinterpret_cast<const int4*>(g1 + 16);
        }

        const int jt   = 2 * s + jhalf;
        const char* bb = (const char*)&hbuf[s & 1][jhalf][0];
#pragma unroll
        for (int kk = 0; kk < 2; ++kk) {
            // sd slice: 16-lane groups read identical 16B -> broadcast, free
            float p[8];
            *reinterpret_cast<float4*>(&p[0]) =
                *reinterpret_cast<const float4*>(&sd[jt * 64 + kk * 32 + kg * 8]);
            *reinterpret_cast<float4*>(&p[4]) =
                *reinterpret_cast<const float4*>(&sd[jt * 64 + kk * 32 + kg * 8 + 4]);

            // A-frag: P[m][k] = exp(leaky(ss + sd[k]) - m_i), bf16
            bf16x8 A;
#pragma unroll
            for (int r = 0; r < 8; ++r) {
                float tt = ss + p[r];
                float l  = fmaxf(tt, NEG_SLOPE * tt);
                float w  = __expf(l + negm);          // in (0, 1]
                A[r] = (short)__builtin_bit_cast(unsigned short, __float2bfloat16(w));
            }

            accD = __builtin_amdgcn_mfma_f32_16x16x32_bf16(A, ones, accD, 0, 0, 0);
#pragma unroll
            for (int t = 0; t < 4; ++t) {
                bf16x8 B = *reinterpret_cast<const bf16x8*>(
                    bb + (t * 2 + kk) * 1024 + lane * 16);
                accC[t] = __builtin_amdgcn_mfma_f32_16x16x32_bf16(A, B, accC[t], 0, 0, 0);
            }
        }

        // write-late: land next tiles in the other buffer, one barrier/step
        if (s < 7) {
            hbuf[(s + 1) & 1][0][tid * 2]     = n00;
            hbuf[(s + 1) & 1][0][tid * 2 + 1] = n01;
            hbuf[(s + 1) & 1][1][tid * 2]     = n10;
            hbuf[(s + 1) & 1][1][tid * 2 + 1] = n11;
        }
        __syncthreads();
    }

    // ---- cross-jhalf combine via LDS (hbuf is free now) ----
    // comb_num: [2][16][68] f32 (padded: kg-groups land 2-way = free banks)
    float* comb = (float*)&hbuf[0][0][0];
    float* cden = comb + 2 * 16 * 68;
    if (jhalf == 1) {
#pragma unroll
        for (int reg = 0; reg < 4; ++reg) {
            int rrow = rowhalf * 16 + kg * 4 + reg;
#pragma unroll
            for (int t = 0; t < 4; ++t)
                comb[rrow * 68 + t * 16 + m] = accC[t][reg];
            if (m == 0) cden[rrow] = accD[reg];
        }
    }
    __syncthreads();
    if (jhalf == 0) {
#pragma unroll
        for (int reg = 0; reg < 4; ++reg) {
            int rrow = rowhalf * 16 + kg * 4 + reg;
            float den = accD[reg] + cden[rrow];
            float inv = 1.0f / den;
            const size_t ob = (nbase + i0 + rowhalf * 16 + kg * 4 + reg) * H_D;
#pragma unroll
            for (int t = 0; t < 4; ++t)
                out[ob + t * 16 + m] = (accC[t][reg] + comb[rrow * 68 + t * 16 + m]) * inv;
        }
    }
}

extern "C" void kernel_launch(void* const* d_in, const int* in_sizes, int n_in,
                              void* d_out, int out_size, void* d_ws, size_t ws_size,
                              hipStream_t stream) {
    const float* feat = (const float*)d_in[0];  // (32,1024,128)
    const float* W    = (const float*)d_in[1];  // (64,128)
    const float* a    = (const float*)d_in[2];  // (1,128)
    float* out = (float*)d_out;                 // (32,1024,64)

    __hip_bfloat16* hT = (__hip_bfloat16*)d_ws;          // NV*64 bf16 = 4 MB
    float* s_src = (float*)(hT + (size_t)NV * H_D);      // NV floats
    float* s_dst = s_src + NV;                           // NV floats

    gat_h_mfma<<<NV / 64, 256, 0, stream>>>(feat, W, a, hT, s_src, s_dst);
    gat_attn_mfma<<<N_G * (V_N / 32), 256, 0, stream>>>(hT, s_src, s_dst, out);
}

// Round 12
// 86.976 us; speedup vs baseline: 1.8820x; 1.0153x over previous
//
#include <hip/hip_runtime.h>
#include <hip/hip_bf16.h>

#define NEG_SLOPE 0.01f
#define LOG2E 1.44269504088896340736f

constexpr int N_G  = 32;    // graphs
constexpr int V_N  = 1024;  // nodes per graph
constexpr int F_IN = 128;
constexpr int H_D  = 64;
constexpr int NV   = N_G * V_N;  // 32768

typedef __attribute__((ext_vector_type(8))) short bf16x8;  // 8 bf16 (4 VGPRs)
typedef __attribute__((ext_vector_type(4))) float f32x4;   // MFMA C/D
typedef __attribute__((ext_vector_type(4))) unsigned int u32x4;

__device__ __forceinline__ float bf16bits_to_f32(unsigned short u) {
    unsigned int x = ((unsigned int)u) << 16;
    return __builtin_bit_cast(float, x);
}
__device__ __forceinline__ unsigned short f32_to_bf16bits(float f) {
    return __builtin_bit_cast(unsigned short, __float2bfloat16(f));
}
__device__ __forceinline__ float fast_exp2(float x) {
#if __has_builtin(__builtin_amdgcn_exp2f)
    return __builtin_amdgcn_exp2f(x);   // bare v_exp_f32 (D = 2^S0)
#else
    float r; asm("v_exp_f32 %0, %1" : "=v"(r) : "v"(x)); return r;
#endif
}

// hT layout (per graph): 16 tiles of 64 j x 64 c, 8KB each, elements in MFMA
// B-frag order: within tile, chunk chi = (t*2+kk)*64 + kg*16 + m  (t=c>>4,
// m=c&15, kk=(j>>5)&1, kg=(j>>3)&3), byte = chi*16 + (j&7)*2. Kernel 2
// reads B-frags at base + (t*2+kk)*1024 + lane*16 -- linear, conflict-free.

// ---------------------------------------------------------------------------
// Kernel 1: h = features @ W^T via bf16x3 split-precision MFMA (f32-accurate).
// (byte-identical to rounds 9/11 -- single-variable experiment on kernel 2)
// ---------------------------------------------------------------------------
__global__ __launch_bounds__(256) void gat_h_mfma(
    const float* __restrict__ feat,   // (NV, 128)
    const float* __restrict__ W,      // (64, 128)
    const float* __restrict__ a,      // (128)
    __hip_bfloat16* __restrict__ hT,  // (32, 64, 1024) bf16, frag-ordered
    float* __restrict__ s_src,        // (NV)
    float* __restrict__ s_dst)        // (NV)
{
    __shared__ __align__(16) float Fs[64][132];          // 33.8KB feat tile (padded)
    __shared__ __align__(16) unsigned short Wf[16384];   // 32KB frag-ordered W hi/lo

    const int tid  = threadIdx.x;
    const int lane = tid & 63;
    const int w    = tid >> 6;
    const int mb   = lane & 15;
    const int kg   = lane >> 4;
    const int r0   = blockIdx.x * 64;

#pragma unroll
    for (int t = 0; t < 8; ++t) {
        int f4  = tid + t * 256;
        int row = f4 >> 5;
        int c4  = (f4 & 31) << 2;
        float4 v = *reinterpret_cast<const float4*>(
            feat + (size_t)(r0 + row) * F_IN + c4);
        *reinterpret_cast<float4*>(&Fs[row][c4]) = v;
    }
#pragma unroll
    for (int t = 0; t < 8; ++t) {
        int f4 = tid + t * 256;
        int n  = f4 >> 5;
        int k4 = (f4 & 31) << 2;
        float4 v = *reinterpret_cast<const float4*>(W + (size_t)n * F_IN + k4);
        int ks  = k4 >> 5;
        int kgw = (k4 >> 3) & 3;
        int rr  = k4 & 7;
        int tt  = n >> 4, nn = n & 15;
        float fv[4] = {v.x, v.y, v.z, v.w};
        unsigned long long ph = 0, pl = 0;
#pragma unroll
        for (int e = 0; e < 4; ++e) {
            unsigned short hb = f32_to_bf16bits(fv[e]);
            unsigned short lb = f32_to_bf16bits(fv[e] - bf16bits_to_f32(hb));
            ph |= ((unsigned long long)hb) << (16 * e);
            pl |= ((unsigned long long)lb) << (16 * e);
        }
        char* base = (char*)Wf;
        int chunk  = (ks * 4 + tt) * 2;
        int off    = (kgw * 16 + nn) * 16 + rr * 2;
        *reinterpret_cast<unsigned long long*>(base + chunk * 1024 + off)       = ph;
        *reinterpret_cast<unsigned long long*>(base + (chunk + 1) * 1024 + off) = pl;
    }
    __syncthreads();

    f32x4 acc[4];
#pragma unroll
    for (int t = 0; t < 4; ++t) acc[t] = (f32x4){0.f, 0.f, 0.f, 0.f};

    const char* wfb = (const char*)Wf;
#pragma unroll
    for (int ks = 0; ks < 4; ++ks) {
        float af[8];
        *reinterpret_cast<float4*>(&af[0]) =
            *reinterpret_cast<const float4*>(&Fs[w * 16 + mb][ks * 32 + kg * 8]);
        *reinterpret_cast<float4*>(&af[4]) =
            *reinterpret_cast<const float4*>(&Fs[w * 16 + mb][ks * 32 + kg * 8 + 4]);
        bf16x8 Ah, Al;
#pragma unroll
        for (int e = 0; e < 8; ++e) {
            unsigned short hb = f32_to_bf16bits(af[e]);
            Ah[e] = (short)hb;
            Al[e] = (short)f32_to_bf16bits(af[e] - bf16bits_to_f32(hb));
        }
#pragma unroll
        for (int t = 0; t < 4; ++t) {
            bf16x8 Bh = *reinterpret_cast<const bf16x8*>(
                wfb + (size_t)((ks * 4 + t) * 2) * 1024 + lane * 16);
            bf16x8 Bl = *reinterpret_cast<const bf16x8*>(
                wfb + (size_t)((ks * 4 + t) * 2 + 1) * 1024 + lane * 16);
            acc[t] = __builtin_amdgcn_mfma_f32_16x16x32_bf16(Al, Bh, acc[t], 0, 0, 0);
            acc[t] = __builtin_amdgcn_mfma_f32_16x16x32_bf16(Ah, Bl, acc[t], 0, 0, 0);
            acc[t] = __builtin_amdgcn_mfma_f32_16x16x32_bf16(Ah, Bh, acc[t], 0, 0, 0);
        }
    }

    float asrc[4], adst[4];
#pragma unroll
    for (int t = 0; t < 4; ++t) {
        asrc[t] = a[t * 16 + mb];
        adst[t] = a[H_D + t * 16 + mb];
    }
    float ps[4], pd[4];
#pragma unroll
    for (int reg = 0; reg < 4; ++reg) {
        ps[reg] = acc[0][reg] * asrc[0] + acc[1][reg] * asrc[1]
                + acc[2][reg] * asrc[2] + acc[3][reg] * asrc[3];
        pd[reg] = acc[0][reg] * adst[0] + acc[1][reg] * adst[1]
                + acc[2][reg] * adst[2] + acc[3][reg] * adst[3];
    }
#pragma unroll
    for (int off = 1; off < 16; off <<= 1) {
#pragma unroll
        for (int reg = 0; reg < 4; ++reg) {
            ps[reg] += __shfl_xor(ps[reg], off);
            pd[reg] += __shfl_xor(pd[reg], off);
        }
    }
    if (mb == 0) {
#pragma unroll
        for (int reg = 0; reg < 4; ++reg) {
            int j = w * 16 + kg * 4 + reg;
            s_src[r0 + j] = ps[reg];
            s_dst[r0 + j] = pd[reg];
        }
    }

    __syncthreads();
    float (*FsT)[65] = reinterpret_cast<float(*)[65]>(&Fs[0][0]);
#pragma unroll
    for (int t = 0; t < 4; ++t)
#pragma unroll
        for (int reg = 0; reg < 4; ++reg)
            FsT[w * 16 + kg * 4 + reg][t * 16 + mb] = acc[t][reg];
    __syncthreads();

    const int g  = r0 >> 10;
    const int jt = (r0 & (V_N - 1)) >> 6;
    char* tile = (char*)(hT + (size_t)g * H_D * V_N) + (size_t)jt * 8192;
#pragma unroll
    for (int ch = 0; ch < 2; ++ch) {
        int chi = tid * 2 + ch;
        int tp  = chi >> 7;
        int kk  = (chi >> 6) & 1;
        int kgp = (chi >> 4) & 3;
        int mp  = chi & 15;
        int c   = tp * 16 + mp;
        int jb  = kk * 32 + kgp * 8;
        unsigned short outp[8];
#pragma unroll
        for (int rr = 0; rr < 8; ++rr) outp[rr] = f32_to_bf16bits(FsT[jb + rr][c]);
        *reinterpret_cast<int4*>(tile + (size_t)chi * 16) =
            *reinterpret_cast<const int4*>(outp);
    }
}

// ---------------------------------------------------------------------------
// Kernel 2 v3: fused softmax + PV via MFMA, j-split wave-pairs (round-9
// structure) + log2-domain P-gen (4 VALU-class ops/element):
//   sd2 = sd*log2e staged; per-row c1 = ss2+negm2, c0 = 0.01*ss2+negm2.
//   max/positive-scale commute: leaky(x)*log2e - m2 = max(c1+sd2, c0+0.01*sd2)
//   -> v_add + v_fma + v_max + bare v_exp (HW exp2). P pairs packed with
//   v_cvt_pk_bf16_f32 straight into A-frag words.
// ---------------------------------------------------------------------------
__global__ __launch_bounds__(256) void gat_attn_mfma(
    const __hip_bfloat16* __restrict__ hT, // (32, 64, 1024) frag-ordered
    const float* __restrict__ s_src,       // (NV)
    const float* __restrict__ s_dst,       // (NV)
    float* __restrict__ out)               // (NV, 64)
{
    __shared__ float sd[V_N];   // 4 KB, holds sd2 = s_dst * log2e
    __shared__ float wred[4];
    __shared__ __align__(16) int4 hbuf[2][2][512];  // [buf][jpar][...] 32 KB

    const int tid   = threadIdx.x;
    const int lane  = tid & 63;
    const int wv    = tid >> 6;
    const int rowhalf = wv & 1;
    const int jhalf   = wv >> 1;
    const int m     = lane & 15;   // A row (=P row) / D col
    const int kg    = lane >> 4;   // k-group
    const int n     = blockIdx.x >> 5;
    const int i0    = (blockIdx.x & 31) * 32;
    const size_t nbase = (size_t)n * V_N;

    const char* hTg = (const char*)(hT + (size_t)n * H_D * V_N);

    // stage sd2 = s_dst * log2e, and its max (scaled domain; log2e>0 monotone)
    float lm;
    {
        float4 v = *reinterpret_cast<const float4*>(s_dst + nbase + tid * 4);
        v.x *= LOG2E; v.y *= LOG2E; v.z *= LOG2E; v.w *= LOG2E;
        *reinterpret_cast<float4*>(&sd[tid * 4]) = v;
        lm = fmaxf(fmaxf(v.x, v.y), fmaxf(v.z, v.w));
    }
#pragma unroll
    for (int off = 32; off >= 1; off >>= 1)
        lm = fmaxf(lm, __shfl_xor(lm, off));
    if (lane == 0) wred[wv] = lm;

    const float ss2 = s_src[nbase + i0 + rowhalf * 16 + m] * LOG2E;

    // prologue: stage tiles 0 and 1 into buf 0 (coalesced 32B/thread/tile)
#pragma unroll
    for (int par = 0; par < 2; ++par) {
        const char* g = hTg + (size_t)par * 8192 + tid * 32;
        hbuf[0][par][tid * 2]     = *reinterpret_cast<const int4*>(g);
        hbuf[0][par][tid * 2 + 1] = *reinterpret_cast<const int4*>(g + 16);
    }
    __syncthreads();

    const float M2    = fmaxf(fmaxf(wred[0], wred[1]), fmaxf(wred[2], wred[3]));
    const float t2    = ss2 + M2;
    const float negm2 = -fmaxf(t2, NEG_SLOPE * t2);  // -rowmax, scaled domain
    const float c1    = ss2 + negm2;                 // pos-branch row constant
    const float c0    = fmaf(NEG_SLOPE, ss2, negm2); // neg-branch row constant

    f32x4 accC[4];
    f32x4 accD = {0.f, 0.f, 0.f, 0.f};
#pragma unroll
    for (int t = 0; t < 4; ++t) accC[t] = (f32x4){0.f, 0.f, 0.f, 0.f};

    bf16x8 ones;
#pragma unroll
    for (int r = 0; r < 8; ++r) ones[r] = (short)0x3F80;  // 1.0 bf16

    for (int s = 0; s < 8; ++s) {
        // issue next step's 2 tiles early (L2 latency hides under compute)
        int4 n00, n01, n10, n11;
        if (s < 7) {
            const char* g0 = hTg + (size_t)(2 * s + 2) * 8192 + tid * 32;
            const char* g1 = hTg + (size_t)(2 * s + 3) * 8192 + tid * 32;
            n00 = *reinterpret_cast<const int4*>(g0);
            n01 = *reinterpret_cast<const int4*>(g0 + 16);
            n10 = *reinterpret_cast<const int4*>(g1);
            n11 = *reinterpret_cast<const int4*>(g1 + 16);
        }

        const int jt   = 2 * s + jhalf;
        const char* bb = (const char*)&hbuf[s & 1][jhalf][0];
#pragma unroll
        for (int kk = 0; kk < 2; ++kk) {
            // sd2 slice: 16-lane groups read identical 16B -> broadcast, free
            float p[8];
            *reinterpret_cast<float4*>(&p[0]) =
                *reinterpret_cast<const float4*>(&sd[jt * 64 + kk * 32 + kg * 8]);
            *reinterpret_cast<float4*>(&p[4]) =
                *reinterpret_cast<const float4*>(&sd[jt * 64 + kk * 32 + kg * 8 + 4]);

            // P[m][k] = exp2(max(c1 + sd2, c0 + 0.01*sd2)) : add+fma+max+exp
            float wexp[8];
#pragma unroll
            for (int r = 0; r < 8; ++r) {
                float av = c1 + p[r];
                float bv = fmaf(NEG_SLOPE, p[r], c0);
                wexp[r] = fast_exp2(fmaxf(av, bv));
            }
            // pack pairs straight into A-frag words (RNE, same as cvt chain)
            unsigned int w01, w23, w45, w67;
            asm("v_cvt_pk_bf16_f32 %0, %1, %2" : "=v"(w01) : "v"(wexp[0]), "v"(wexp[1]));
            asm("v_cvt_pk_bf16_f32 %0, %1, %2" : "=v"(w23) : "v"(wexp[2]), "v"(wexp[3]));
            asm("v_cvt_pk_bf16_f32 %0, %1, %2" : "=v"(w45) : "v"(wexp[4]), "v"(wexp[5]));
            asm("v_cvt_pk_bf16_f32 %0, %1, %2" : "=v"(w67) : "v"(wexp[6]), "v"(wexp[7]));
            u32x4 au = {w01, w23, w45, w67};
            bf16x8 A = __builtin_bit_cast(bf16x8, au);

            accD = __builtin_amdgcn_mfma_f32_16x16x32_bf16(A, ones, accD, 0, 0, 0);
#pragma unroll
            for (int t = 0; t < 4; ++t) {
                bf16x8 B = *reinterpret_cast<const bf16x8*>(
                    bb + (t * 2 + kk) * 1024 + lane * 16);
                accC[t] = __builtin_amdgcn_mfma_f32_16x16x32_bf16(A, B, accC[t], 0, 0, 0);
            }
        }

        // write-late: land next tiles in the other buffer, one barrier/step
        if (s < 7) {
            hbuf[(s + 1) & 1][0][tid * 2]     = n00;
            hbuf[(s + 1) & 1][0][tid * 2 + 1] = n01;
            hbuf[(s + 1) & 1][1][tid * 2]     = n10;
            hbuf[(s + 1) & 1][1][tid * 2 + 1] = n11;
        }
        __syncthreads();
    }

    // ---- cross-jhalf combine via LDS (hbuf is free now) ----
    float* comb = (float*)&hbuf[0][0][0];
    float* cden = comb + 2 * 16 * 68;
    if (jhalf == 1) {
#pragma unroll
        for (int reg = 0; reg < 4; ++reg) {
            int rrow = rowhalf * 16 + kg * 4 + reg;
#pragma unroll
            for (int t = 0; t < 4; ++t)
                comb[rrow * 68 + t * 16 + m] = accC[t][reg];
            if (m == 0) cden[rrow] = accD[reg];
        }
    }
    __syncthreads();
    if (jhalf == 0) {
#pragma unroll
        for (int reg = 0; reg < 4; ++reg) {
            int rrow = rowhalf * 16 + kg * 4 + reg;
            float den = accD[reg] + cden[rrow];
            float inv = 1.0f / den;
            const size_t ob = (nbase + i0 + rowhalf * 16 + kg * 4 + reg) * H_D;
#pragma unroll
            for (int t = 0; t < 4; ++t)
                out[ob + t * 16 + m] = (accC[t][reg] + comb[rrow * 68 + t * 16 + m]) * inv;
        }
    }
}

extern "C" void kernel_launch(void* const* d_in, const int* in_sizes, int n_in,
                              void* d_out, int out_size, void* d_ws, size_t ws_size,
                              hipStream_t stream) {
    const float* feat = (const float*)d_in[0];  // (32,1024,128)
    const float* W    = (const float*)d_in[1];  // (64,128)
    const float* a    = (const float*)d_in[2];  // (1,128)
    float* out = (float*)d_out;                 // (32,1024,64)

    __hip_bfloat16* hT = (__hip_bfloat16*)d_ws;          // NV*64 bf16 = 4 MB
    float* s_src = (float*)(hT + (size_t)NV * H_D);      // NV floats
    float* s_dst = s_src + NV;                           // NV floats

    gat_h_mfma<<<NV / 64, 256, 0, stream>>>(feat, W, a, hT, s_src, s_dst);
    gat_attn_mfma<<<N_G * (V_N / 32), 256, 0, stream>>>(hT, s_src, s_dst, out);
}